// Round 6
// baseline (300.006 us; speedup 1.0000x reference)
//
#include <hip/hip_runtime.h>
#include <hip/hip_bf16.h>
#include <math.h>
#include <stdint.h>

// ---------------------------------------------------------------------------
// MaskedContextSelector, round 6: occupancy + barrier amortization.
//   K0a prep_hs  : hs_hi = bf16(hs); hsT_hi/lo = transposed bf16 hi/lo split
//   K0b cast_w   : Wq,Wk -> bf16
//   K1  proj_mfma: Q,K = bf16MFMA(hs_hi @ W^T) + bias -> bf16
//   K2a zpart    : z[b,h,t] via causal 128x128 LDS-staged MFMA tiles
//   K2b elgen    : causal 64x64 tiles, HEAD-PAIR loop (8 iters, 16 barriers)
//   K3  out_mfma : out = (ELh@Hh + ELh@Hl + ELl@Hh)/L, BK=32, 30.7KB LDS
//                  -> 5 blocks/CU
// ---------------------------------------------------------------------------

#define B_   2
#define T_   2048
#define E_   1024
#define NH_  16
#define DH_  64
#define M_   (B_ * T_)
#define SCALE_ 0.125f

typedef __attribute__((ext_vector_type(8))) short bf16x8;
typedef __attribute__((ext_vector_type(4))) float f32x4;

__device__ __forceinline__ short f2bf(float x) {
  __hip_bfloat16 h = __float2bfloat16(x);
  return *reinterpret_cast<short*>(&h);
}
__device__ __forceinline__ float bf2f(short x) {
  __hip_bfloat16 h = *reinterpret_cast<__hip_bfloat16*>(&x);
  return __bfloat162float(h);
}
// triangular pair index -> (ti, si), si <= ti
__device__ __forceinline__ void tri_decode(int idx, int& ti, int& si) {
  int t = (int)((sqrtf(8.0f * (float)idx + 1.0f) - 1.0f) * 0.5f);
  while ((t + 1) * (t + 2) / 2 <= idx) ++t;
  while (t * (t + 1) / 2 > idx) --t;
  ti = t;
  si = idx - t * (t + 1) / 2;
}

// ------------------- K0a: cast + transpose hidden states -------------------
__global__ __launch_bounds__(256) void prep_hs(
    const float* __restrict__ hs, short* __restrict__ hs_hi,
    short* __restrict__ hsT_hi, short* __restrict__ hsT_lo)
{
  const int b = blockIdx.z;
  const int s0 = blockIdx.x * 64, e0 = blockIdx.y * 64;
  __shared__ float tile[64][65];
  const int tid = threadIdx.x;
  const int r = tid >> 4, c4 = (tid & 15) * 4;

  #pragma unroll
  for (int rr = 0; rr < 64; rr += 16) {
    const float4 v = *(const float4*)(hs + (size_t)(b * T_ + s0 + r + rr) * E_ + e0 + c4);
    ushort4 o;
    o.x = (unsigned short)f2bf(v.x); o.y = (unsigned short)f2bf(v.y);
    o.z = (unsigned short)f2bf(v.z); o.w = (unsigned short)f2bf(v.w);
    *(ushort4*)(hs_hi + (size_t)(b * T_ + s0 + r + rr) * E_ + e0 + c4) = o;
    tile[r + rr][c4 + 0] = v.x; tile[r + rr][c4 + 1] = v.y;
    tile[r + rr][c4 + 2] = v.z; tile[r + rr][c4 + 3] = v.w;
  }
  __syncthreads();
  #pragma unroll
  for (int rr = 0; rr < 64; rr += 16) {
    ushort4 oh, ol;
    #pragma unroll
    for (int j = 0; j < 4; ++j) {
      const float v = tile[c4 + j][r + rr];
      const short hi = f2bf(v);
      const short lo = f2bf(v - bf2f(hi));
      ((unsigned short*)&oh)[j] = (unsigned short)hi;
      ((unsigned short*)&ol)[j] = (unsigned short)lo;
    }
    const size_t dst = (size_t)(b * E_ + e0 + r + rr) * T_ + s0 + c4;
    *(ushort4*)(hsT_hi + dst) = oh;
    *(ushort4*)(hsT_lo + dst) = ol;
  }
}

// ------------------------------ K0b: cast W --------------------------------
__global__ __launch_bounds__(256) void cast_w(
    const float* __restrict__ Wq, const float* __restrict__ Wk,
    short* __restrict__ Wqb, short* __restrict__ Wkb)
{
  const size_t i = ((size_t)blockIdx.x * 256 + threadIdx.x) * 4;
  const float4 q = *(const float4*)(Wq + i);
  const float4 k = *(const float4*)(Wk + i);
  ushort4 oq, ok;
  oq.x = (unsigned short)f2bf(q.x); oq.y = (unsigned short)f2bf(q.y);
  oq.z = (unsigned short)f2bf(q.z); oq.w = (unsigned short)f2bf(q.w);
  ok.x = (unsigned short)f2bf(k.x); ok.y = (unsigned short)f2bf(k.y);
  ok.z = (unsigned short)f2bf(k.z); ok.w = (unsigned short)f2bf(k.w);
  *(ushort4*)(Wqb + i) = oq;
  *(ushort4*)(Wkb + i) = ok;
}

// --------------------------- K1: projection MFMA ---------------------------
__global__ __launch_bounds__(256) void proj_mfma(
    const short* __restrict__ hsb,
    const short* __restrict__ Wqb, const short* __restrict__ Wkb,
    const float* __restrict__ bq, const float* __restrict__ bk,
    short* __restrict__ Qb, short* __restrict__ Kb)
{
  const int nt = blockIdx.x;
  const int m0 = blockIdx.y * 128;
  const bool isK = nt >= 8;
  const short* __restrict__ Wsel = isK ? Wkb : Wqb;
  const float* __restrict__ bsel = isK ? bk : bq;
  short* __restrict__ Csel = isK ? Kb : Qb;
  const int nb = (nt & 7) * 128;

  __shared__ __align__(16) unsigned short Asm[128][72];
  __shared__ __align__(16) unsigned short Bsm[128][72];

  const int tid = threadIdx.x;
  const int wid = tid >> 6, l = tid & 63;
  const int lg = l >> 4, li = l & 15;
  const int wm = (wid >> 1) * 64, wn = (wid & 1) * 64;
  const int srow = tid >> 1, shalf = (tid & 1) * 32;

  f32x4 acc[4][4];
  #pragma unroll
  for (int i = 0; i < 4; ++i)
    #pragma unroll
    for (int j = 0; j < 4; ++j) acc[i][j] = (f32x4){0.f, 0.f, 0.f, 0.f};

  for (int kt = 0; kt < E_; kt += 64) {
    const short* ga = hsb + (size_t)(m0 + srow) * E_ + kt + shalf;
    const short* gb = Wsel + (size_t)(nb + srow) * E_ + kt + shalf;
    bf16x8 a0 = *(const bf16x8*)(ga);      bf16x8 a1 = *(const bf16x8*)(ga + 8);
    bf16x8 a2 = *(const bf16x8*)(ga + 16); bf16x8 a3 = *(const bf16x8*)(ga + 24);
    bf16x8 b0 = *(const bf16x8*)(gb);      bf16x8 b1 = *(const bf16x8*)(gb + 8);
    bf16x8 b2 = *(const bf16x8*)(gb + 16); bf16x8 b3 = *(const bf16x8*)(gb + 24);
    __syncthreads();
    *(bf16x8*)&Asm[srow][shalf + 0]  = a0; *(bf16x8*)&Asm[srow][shalf + 8]  = a1;
    *(bf16x8*)&Asm[srow][shalf + 16] = a2; *(bf16x8*)&Asm[srow][shalf + 24] = a3;
    *(bf16x8*)&Bsm[srow][shalf + 0]  = b0; *(bf16x8*)&Bsm[srow][shalf + 8]  = b1;
    *(bf16x8*)&Bsm[srow][shalf + 16] = b2; *(bf16x8*)&Bsm[srow][shalf + 24] = b3;
    __syncthreads();
    #pragma unroll
    for (int kb = 0; kb < 2; ++kb) {
      bf16x8 af[4], bfv[4];
      #pragma unroll
      for (int i = 0; i < 4; ++i)
        af[i] = *(const bf16x8*)&Asm[wm + i * 16 + li][kb * 32 + lg * 8];
      #pragma unroll
      for (int j = 0; j < 4; ++j)
        bfv[j] = *(const bf16x8*)&Bsm[wn + j * 16 + li][kb * 32 + lg * 8];
      #pragma unroll
      for (int i = 0; i < 4; ++i)
        #pragma unroll
        for (int j = 0; j < 4; ++j)
          acc[i][j] = __builtin_amdgcn_mfma_f32_16x16x32_bf16(af[i], bfv[j], acc[i][j], 0, 0, 0);
    }
  }

  #pragma unroll
  for (int j = 0; j < 4; ++j) {
    const int n = nb + wn + j * 16 + li;
    const float bv = bsel[n];
    #pragma unroll
    for (int i = 0; i < 4; ++i) {
      #pragma unroll
      for (int r = 0; r < 4; ++r) {
        const int m = m0 + wm + i * 16 + lg * 4 + r;
        Csel[(size_t)m * E_ + n] = f2bf(acc[i][j][r] + bv);
      }
    }
  }
}

// ----------------- K2a: z sums via causal 128x128 GEMM tiles ---------------
__global__ __launch_bounds__(256) void zpart_kernel(
    const short* __restrict__ Qb, const short* __restrict__ Kb,
    const int* __restrict__ clen, float* __restrict__ zs)
{
  const int bh = blockIdx.y;
  const int b = bh >> 4, h = bh & 15;
  int ti, si;
  tri_decode(blockIdx.x, ti, si);
  const int t0 = ti * 128, s0 = si * 128;
  const int tid = threadIdx.x;
  const int w = tid >> 6, l = tid & 63, lg = l >> 4, li = l & 15;
  const int wm = (w >> 1) * 64, wn = (w & 1) * 64;

  __shared__ __align__(16) unsigned short Qs[128][72];
  __shared__ __align__(16) unsigned short Ks[128][72];
  __shared__ int len_s[128];

  {
    const int row = tid >> 1, half = (tid & 1) * 32;
    const short* gq = Qb + (size_t)(b * T_ + t0 + row) * E_ + h * DH_ + half;
    const short* gk = Kb + (size_t)(b * T_ + s0 + row) * E_ + h * DH_ + half;
    *(bf16x8*)&Qs[row][half + 0]  = *(const bf16x8*)(gq + 0);
    *(bf16x8*)&Qs[row][half + 8]  = *(const bf16x8*)(gq + 8);
    *(bf16x8*)&Qs[row][half + 16] = *(const bf16x8*)(gq + 16);
    *(bf16x8*)&Qs[row][half + 24] = *(const bf16x8*)(gq + 24);
    *(bf16x8*)&Ks[row][half + 0]  = *(const bf16x8*)(gk + 0);
    *(bf16x8*)&Ks[row][half + 8]  = *(const bf16x8*)(gk + 8);
    *(bf16x8*)&Ks[row][half + 16] = *(const bf16x8*)(gk + 16);
    *(bf16x8*)&Ks[row][half + 24] = *(const bf16x8*)(gk + 24);
  }
  if (tid < 128) {
    int L = clen[t0 + tid];
    len_s[tid] = L < 0 ? 0 : (L > T_ ? T_ : L);
  }
  __syncthreads();

  f32x4 acc[4][4];
  #pragma unroll
  for (int i = 0; i < 4; ++i)
    #pragma unroll
    for (int j = 0; j < 4; ++j) acc[i][j] = (f32x4){0.f, 0.f, 0.f, 0.f};

  #pragma unroll
  for (int kb = 0; kb < 2; ++kb) {
    bf16x8 af[4], bfv[4];
    #pragma unroll
    for (int i = 0; i < 4; ++i)
      af[i] = *(const bf16x8*)&Qs[wm + i * 16 + li][kb * 32 + lg * 8];
    #pragma unroll
    for (int j = 0; j < 4; ++j)
      bfv[j] = *(const bf16x8*)&Ks[wn + j * 16 + li][kb * 32 + lg * 8];
    #pragma unroll
    for (int i = 0; i < 4; ++i)
      #pragma unroll
      for (int j = 0; j < 4; ++j)
        acc[i][j] = __builtin_amdgcn_mfma_f32_16x16x32_bf16(af[i], bfv[j], acc[i][j], 0, 0, 0);
  }

  float zp[4][4];
  #pragma unroll
  for (int i = 0; i < 4; ++i)
    #pragma unroll
    for (int r = 0; r < 4; ++r) zp[i][r] = 0.f;

  #pragma unroll
  for (int i = 0; i < 4; ++i) {
    int lenr[4];
    #pragma unroll
    for (int r = 0; r < 4; ++r) lenr[r] = len_s[wm + i * 16 + lg * 4 + r];
    #pragma unroll
    for (int j = 0; j < 4; ++j) {
      const int scol = s0 + wn + j * 16 + li;
      #pragma unroll
      for (int r = 0; r < 4; ++r)
        if (scol < lenr[r]) zp[i][r] += __expf(acc[i][j][r] * SCALE_);
    }
  }

  #pragma unroll
  for (int i = 0; i < 4; ++i)
    #pragma unroll
    for (int r = 0; r < 4; ++r) {
      float v = zp[i][r];
      v += __shfl_xor(v, 1); v += __shfl_xor(v, 2);
      v += __shfl_xor(v, 4); v += __shfl_xor(v, 8);
      if (li == 0 && v > 0.f)
        atomicAdd(&zs[(size_t)bh * T_ + t0 + wm + i * 16 + lg * 4 + r], v);
    }
}

// ---------- K2b: causal 64x64 tiles, head-PAIR loop, EL + L ----------------
__global__ __launch_bounds__(256) void elgen_kernel(
    const short* __restrict__ Qb, const short* __restrict__ Kb,
    const float* __restrict__ zs, const float* __restrict__ gum,
    const int* __restrict__ clen,
    short* __restrict__ ELh, short* __restrict__ ELl, float* __restrict__ Lws)
{
  const int b = blockIdx.y;
  int ti, si;
  tri_decode(blockIdx.x, ti, si);
  const int t0 = ti * 64, s0 = si * 64;
  const int tid = threadIdx.x;
  const int w = tid >> 6, l = tid & 63, lg = l >> 4, li = l & 15;
  const int wr = (w >> 1) * 32, wc = (w & 1) * 32;

  __shared__ __align__(16) unsigned short Qs[64][136];   // head pair: 128 k-dims
  __shared__ __align__(16) unsigned short Ks[64][136];
  __shared__ float rz_s[16][64];
  __shared__ int len_s[64];

  if (tid < 64) {
    int L = clen[t0 + tid];
    len_s[tid] = L < 0 ? 0 : (L > T_ ? T_ : L);
  }
  #pragma unroll
  for (int q = 0; q < 4; ++q) {
    const int e = tid * 4 + q;                    // 0..1023 = h*64 + tl
    const float zv = zs[(size_t)(b * NH_ + (e >> 6)) * T_ + t0 + (e & 63)];
    rz_s[e >> 6][e & 63] = (zv > 0.f) ? 1.f / zv : 0.f;
  }

  f32x4 aw[2][2];
  #pragma unroll
  for (int i = 0; i < 2; ++i)
    #pragma unroll
    for (int j = 0; j < 2; ++j) aw[i][j] = (f32x4){0.f, 0.f, 0.f, 0.f};

  const int srow = tid >> 2, sch = (tid & 3) * 32;

  for (int p = 0; p < 8; ++p) {                   // head pair (2p, 2p+1)
    __syncthreads();   // p=0: covers len_s/rz_s writes; p>0: protect LDS reuse
    const short* gq = Qb + (size_t)(b * T_ + t0 + srow) * E_ + p * 128 + sch;
    const short* gk = Kb + (size_t)(b * T_ + s0 + srow) * E_ + p * 128 + sch;
    *(bf16x8*)&Qs[srow][sch + 0]  = *(const bf16x8*)(gq);
    *(bf16x8*)&Qs[srow][sch + 8]  = *(const bf16x8*)(gq + 8);
    *(bf16x8*)&Qs[srow][sch + 16] = *(const bf16x8*)(gq + 16);
    *(bf16x8*)&Qs[srow][sch + 24] = *(const bf16x8*)(gq + 24);
    *(bf16x8*)&Ks[srow][sch + 0]  = *(const bf16x8*)(gk);
    *(bf16x8*)&Ks[srow][sch + 8]  = *(const bf16x8*)(gk + 8);
    *(bf16x8*)&Ks[srow][sch + 16] = *(const bf16x8*)(gk + 16);
    *(bf16x8*)&Ks[srow][sch + 24] = *(const bf16x8*)(gk + 24);
    __syncthreads();

    f32x4 sc[2][2][2];                            // [head][i][j]
    #pragma unroll
    for (int h2 = 0; h2 < 2; ++h2)
      #pragma unroll
      for (int i = 0; i < 2; ++i)
        #pragma unroll
        for (int j = 0; j < 2; ++j) sc[h2][i][j] = (f32x4){0.f, 0.f, 0.f, 0.f};

    #pragma unroll
    for (int h2 = 0; h2 < 2; ++h2) {
      #pragma unroll
      for (int kb = 0; kb < 2; ++kb) {
        const int kc = h2 * 64 + kb * 32 + lg * 8;
        bf16x8 af[2], bfv[2];
        af[0] = *(const bf16x8*)&Qs[wr + li][kc];
        af[1] = *(const bf16x8*)&Qs[wr + 16 + li][kc];
        bfv[0] = *(const bf16x8*)&Ks[wc + li][kc];
        bfv[1] = *(const bf16x8*)&Ks[wc + 16 + li][kc];
        #pragma unroll
        for (int i = 0; i < 2; ++i)
          #pragma unroll
          for (int j = 0; j < 2; ++j)
            sc[h2][i][j] = __builtin_amdgcn_mfma_f32_16x16x32_bf16(af[i], bfv[j], sc[h2][i][j], 0, 0, 0);
      }
    }
    #pragma unroll
    for (int i = 0; i < 2; ++i) {
      float rz0[4], rz1[4];
      #pragma unroll
      for (int r = 0; r < 4; ++r) {
        rz0[r] = rz_s[2 * p][wr + i * 16 + lg * 4 + r];
        rz1[r] = rz_s[2 * p + 1][wr + i * 16 + lg * 4 + r];
      }
      #pragma unroll
      for (int j = 0; j < 2; ++j)
        #pragma unroll
        for (int r = 0; r < 4; ++r)
          aw[i][j][r] += __expf(sc[0][i][j][r] * SCALE_) * rz0[r] +
                         __expf(sc[1][i][j][r] * SCALE_) * rz1[r];
    }
  }

  // epilogue: gumbel -> EL hi/lo stores + L row partials
  #pragma unroll
  for (int i = 0; i < 2; ++i) {
    float lrow[4] = {0.f, 0.f, 0.f, 0.f};
    #pragma unroll
    for (int r = 0; r < 4; ++r) {
      const int tl = wr + i * 16 + lg * 4 + r;
      const int lenr = len_s[tl];
      const size_t grow = (size_t)(b * T_ + t0 + tl) * T_;
      #pragma unroll
      for (int j = 0; j < 2; ++j) {
        const int scol = s0 + wc + j * 16 + li;
        float e = 0.f;
        if (scol < lenr) {
          const float u = gum[grow + scol];
          const float g = -__logf(-__logf(u));
          e = expf((aw[i][j][r] * (1.f / NH_) + g) * 0.5f);   // /TAU, TAU=2
        }
        const short hi = f2bf(e);
        const short lo = f2bf(e - bf2f(hi));
        ELh[grow + scol] = hi;
        ELl[grow + scol] = lo;
        lrow[r] += e;
      }
    }
    #pragma unroll
    for (int r = 0; r < 4; ++r) {
      float v = lrow[r];
      v += __shfl_xor(v, 1); v += __shfl_xor(v, 2);
      v += __shfl_xor(v, 4); v += __shfl_xor(v, 8);
      if (li == 0 && v > 0.f)
        atomicAdd(&Lws[(size_t)(b * T_) + t0 + wr + i * 16 + lg * 4 + r], v);
    }
  }
}

// ----------------------- K3: output MFMA + normalize -----------------------
// 64x128 tile, BK=32, 30.7KB LDS -> 5 blocks/CU.
__global__ __launch_bounds__(256) void out_mfma(
    const short* __restrict__ ELh, const short* __restrict__ ELl,
    const short* __restrict__ HTh, const short* __restrict__ HTl,
    const float* __restrict__ Lws, const int* __restrict__ clen,
    float* __restrict__ outp)
{
  const int e0 = blockIdx.x * 128;
  const int m0 = ((int)gridDim.y - 1 - (int)blockIdx.y) * 64;   // long tiles first
  const int b = m0 >> 11;
  const int tl0 = m0 & (T_ - 1);
  const int tid = threadIdx.x;
  const int w = tid >> 6, l = tid & 63, lg = l >> 4, li = l & 15;
  const int wr = (w >> 1) * 32, wc = (w & 1) * 64;

  __shared__ __align__(16) unsigned short Ah[64][40], Al[64][40];
  __shared__ __align__(16) unsigned short Bh[128][40], Bl[128][40];
  __shared__ int smax_sh;

  if (tid == 0) smax_sh = 0;
  __syncthreads();
  if (tid < 64) {
    int L = clen[tl0 + tid];
    L = L < 0 ? 0 : (L > T_ ? T_ : L);
    atomicMax(&smax_sh, L);
  }
  __syncthreads();
  const int kend = (smax_sh + 31) & ~31;

  const int ar = tid >> 2, ac = (tid & 3) * 8;     // A: 64x32
  const int br = tid >> 1, bc = (tid & 1) * 16;    // B: 128x32

  f32x4 acc[2][4];
  #pragma unroll
  for (int i = 0; i < 2; ++i)
    #pragma unroll
    for (int j = 0; j < 4; ++j) acc[i][j] = (f32x4){0.f, 0.f, 0.f, 0.f};

  for (int s0 = 0; s0 < kend; s0 += 32) {
    const size_t asrc = (size_t)(m0 + ar) * T_ + s0 + ac;
    const size_t bsrc = (size_t)(b * E_ + e0 + br) * T_ + s0 + bc;
    const bf16x8 vah  = *(const bf16x8*)(ELh + asrc);
    const bf16x8 val  = *(const bf16x8*)(ELl + asrc);
    const bf16x8 vbh0 = *(const bf16x8*)(HTh + bsrc);
    const bf16x8 vbh1 = *(const bf16x8*)(HTh + bsrc + 8);
    const bf16x8 vbl0 = *(const bf16x8*)(HTl + bsrc);
    const bf16x8 vbl1 = *(const bf16x8*)(HTl + bsrc + 8);
    __syncthreads();
    *(bf16x8*)&Ah[ar][ac] = vah;
    *(bf16x8*)&Al[ar][ac] = val;
    *(bf16x8*)&Bh[br][bc] = vbh0; *(bf16x8*)&Bh[br][bc + 8] = vbh1;
    *(bf16x8*)&Bl[br][bc] = vbl0; *(bf16x8*)&Bl[br][bc + 8] = vbl1;
    __syncthreads();
    bf16x8 ah[2], al[2], bh[4], bl[4];
    #pragma unroll
    for (int i = 0; i < 2; ++i) {
      ah[i] = *(const bf16x8*)&Ah[wr + i * 16 + li][lg * 8];
      al[i] = *(const bf16x8*)&Al[wr + i * 16 + li][lg * 8];
    }
    #pragma unroll
    for (int j = 0; j < 4; ++j) {
      bh[j] = *(const bf16x8*)&Bh[wc + j * 16 + li][lg * 8];
      bl[j] = *(const bf16x8*)&Bl[wc + j * 16 + li][lg * 8];
    }
    #pragma unroll
    for (int i = 0; i < 2; ++i)
      #pragma unroll
      for (int j = 0; j < 4; ++j) {
        acc[i][j] = __builtin_amdgcn_mfma_f32_16x16x32_bf16(ah[i], bh[j], acc[i][j], 0, 0, 0);
        acc[i][j] = __builtin_amdgcn_mfma_f32_16x16x32_bf16(ah[i], bl[j], acc[i][j], 0, 0, 0);
        acc[i][j] = __builtin_amdgcn_mfma_f32_16x16x32_bf16(al[i], bh[j], acc[i][j], 0, 0, 0);
      }
  }

  #pragma unroll
  for (int i = 0; i < 2; ++i)
    #pragma unroll
    for (int r = 0; r < 4; ++r) {
      const int m = m0 + wr + i * 16 + lg * 4 + r;
      const float Lv = Lws[m];
      const float inv = (Lv > 0.f) ? 1.f / Lv : 0.f;
      #pragma unroll
      for (int j = 0; j < 4; ++j)
        outp[(size_t)m * E_ + e0 + wc + j * 16 + li] = acc[i][j][r] * inv;
    }
}

// ------------------------------- launcher ----------------------------------
extern "C" void kernel_launch(void* const* d_in, const int* in_sizes, int n_in,
                              void* d_out, int out_size, void* d_ws, size_t ws_size,
                              hipStream_t stream) {
  const float* hs  = (const float*)d_in[0];
  const float* Wq  = (const float*)d_in[1];
  const float* bq  = (const float*)d_in[2];
  const float* Wk  = (const float*)d_in[3];
  const float* bk  = (const float*)d_in[4];
  const float* gum = (const float*)d_in[5];
  const int*   cl  = (const int*)d_in[6];
  float* out = (float*)d_out;

  short* hs_hi  = (short*)d_ws;
  short* hsT_hi = hs_hi  + (size_t)M_ * E_;
  short* hsT_lo = hsT_hi + (size_t)B_ * E_ * T_;
  short* Wqb    = hsT_lo + (size_t)B_ * E_ * T_;
  short* Wkb    = Wqb + (size_t)E_ * E_;
  short* Qb     = Wkb + (size_t)E_ * E_;
  short* Kb     = Qb + (size_t)M_ * E_;
  short* ELh    = Kb + (size_t)M_ * E_;
  short* ELl    = ELh + (size_t)M_ * T_;
  float* zsws   = (float*)(ELl + (size_t)M_ * T_);
  float* Lw     = zsws + (size_t)B_ * NH_ * T_;
  (void)ws_size; (void)in_sizes; (void)n_in; (void)out_size;

  hipMemsetAsync(zsws, 0, (size_t)B_ * NH_ * T_ * sizeof(float), stream);
  hipMemsetAsync(Lw, 0, (size_t)M_ * sizeof(float), stream);
  prep_hs<<<dim3(T_ / 64, E_ / 64, B_), 256, 0, stream>>>(hs, hs_hi, hsT_hi, hsT_lo);
  cast_w<<<dim3((E_ * E_) / (256 * 4)), 256, 0, stream>>>(Wq, Wk, Wqb, Wkb);
  proj_mfma<<<dim3(16, M_ / 128), 256, 0, stream>>>(hs_hi, Wqb, Wkb, bq, bk, Qb, Kb);
  zpart_kernel<<<dim3(136, B_ * NH_), 256, 0, stream>>>(Qb, Kb, cl, zsws);
  elgen_kernel<<<dim3(528, B_), 256, 0, stream>>>(Qb, Kb, zsws, gum, cl, ELh, ELl, Lw);
  out_mfma<<<dim3(E_ / 128, M_ / 64), 256, 0, stream>>>(
      ELh, ELl, hsT_hi, hsT_lo, Lw, cl, out);
}

// Round 7
// 256.394 us; speedup vs baseline: 1.1701x; 1.1701x over previous
//
#include <hip/hip_runtime.h>
#include <hip/hip_bf16.h>
#include <math.h>
#include <stdint.h>

// ---------------------------------------------------------------------------
// MaskedContextSelector, round 7: full fp16 pipeline (fp16 eps 4.9e-4 beats
// bf16's 3.9e-3 -> single-pass out GEMM, no hi/lo split anywhere).
//   K0a prep_hs  : hs16 = fp16(hs); hsT16 = transposed fp16
//   K0b cast_w   : Wq,Wk -> fp16
//   K1  proj_mfma: Q,K = f16MFMA(hs16 @ W^T) + bias -> fp16
//   K2a zpart    : z[b,h,t] via causal 128x128 LDS-staged f16 MFMA tiles
//   K2b elgen    : causal 64x64 tiles, head-pair loop; EL fp16 single store
//   K3  out_mfma : out = (EL16 @ hsT16)/L, 64x64 tile, BK=64, grid 1024
//                  (4 blocks/CU; round-6 lesson: 512-block grid capped occ)
// ---------------------------------------------------------------------------

#define B_   2
#define T_   2048
#define E_   1024
#define NH_  16
#define DH_  64
#define M_   (B_ * T_)
#define SCALE_ 0.125f

typedef __attribute__((ext_vector_type(8))) _Float16 f16x8;   // 8 fp16 = 4 VGPR
typedef __attribute__((ext_vector_type(4))) float f32x4;

__device__ __forceinline__ short f2h(float x) {
  _Float16 h = (_Float16)x;
  return *reinterpret_cast<short*>(&h);
}
__device__ __forceinline__ float h2f(short s) {
  return (float)(*reinterpret_cast<_Float16*>(&s));
}
// triangular pair index -> (ti, si), si <= ti
__device__ __forceinline__ void tri_decode(int idx, int& ti, int& si) {
  int t = (int)((sqrtf(8.0f * (float)idx + 1.0f) - 1.0f) * 0.5f);
  while ((t + 1) * (t + 2) / 2 <= idx) ++t;
  while (t * (t + 1) / 2 > idx) --t;
  ti = t;
  si = idx - t * (t + 1) / 2;
}

// ------------------- K0a: cast + transpose hidden states -------------------
__global__ __launch_bounds__(256) void prep_hs(
    const float* __restrict__ hs, short* __restrict__ hs16,
    short* __restrict__ hsT16)
{
  const int b = blockIdx.z;
  const int s0 = blockIdx.x * 64, e0 = blockIdx.y * 64;
  __shared__ float tile[64][65];
  const int tid = threadIdx.x;
  const int r = tid >> 4, c4 = (tid & 15) * 4;

  #pragma unroll
  for (int rr = 0; rr < 64; rr += 16) {
    const float4 v = *(const float4*)(hs + (size_t)(b * T_ + s0 + r + rr) * E_ + e0 + c4);
    ushort4 o;
    o.x = (unsigned short)f2h(v.x); o.y = (unsigned short)f2h(v.y);
    o.z = (unsigned short)f2h(v.z); o.w = (unsigned short)f2h(v.w);
    *(ushort4*)(hs16 + (size_t)(b * T_ + s0 + r + rr) * E_ + e0 + c4) = o;
    tile[r + rr][c4 + 0] = v.x; tile[r + rr][c4 + 1] = v.y;
    tile[r + rr][c4 + 2] = v.z; tile[r + rr][c4 + 3] = v.w;
  }
  __syncthreads();
  #pragma unroll
  for (int rr = 0; rr < 64; rr += 16) {
    ushort4 o;
    #pragma unroll
    for (int j = 0; j < 4; ++j)
      ((unsigned short*)&o)[j] = (unsigned short)f2h(tile[c4 + j][r + rr]);
    *(ushort4*)(hsT16 + (size_t)(b * E_ + e0 + r + rr) * T_ + s0 + c4) = o;
  }
}

// ------------------------------ K0b: cast W --------------------------------
__global__ __launch_bounds__(256) void cast_w(
    const float* __restrict__ Wq, const float* __restrict__ Wk,
    short* __restrict__ Wq16, short* __restrict__ Wk16)
{
  const size_t i = ((size_t)blockIdx.x * 256 + threadIdx.x) * 4;
  const float4 q = *(const float4*)(Wq + i);
  const float4 k = *(const float4*)(Wk + i);
  ushort4 oq, ok;
  oq.x = (unsigned short)f2h(q.x); oq.y = (unsigned short)f2h(q.y);
  oq.z = (unsigned short)f2h(q.z); oq.w = (unsigned short)f2h(q.w);
  ok.x = (unsigned short)f2h(k.x); ok.y = (unsigned short)f2h(k.y);
  ok.z = (unsigned short)f2h(k.z); ok.w = (unsigned short)f2h(k.w);
  *(ushort4*)(Wq16 + i) = oq;
  *(ushort4*)(Wk16 + i) = ok;
}

// --------------------------- K1: projection MFMA ---------------------------
__global__ __launch_bounds__(256) void proj_mfma(
    const short* __restrict__ hsb,
    const short* __restrict__ Wq16, const short* __restrict__ Wk16,
    const float* __restrict__ bq, const float* __restrict__ bk,
    short* __restrict__ Qh, short* __restrict__ Kh)
{
  const int nt = blockIdx.x;
  const int m0 = blockIdx.y * 128;
  const bool isK = nt >= 8;
  const short* __restrict__ Wsel = isK ? Wk16 : Wq16;
  const float* __restrict__ bsel = isK ? bk : bq;
  short* __restrict__ Csel = isK ? Kh : Qh;
  const int nb = (nt & 7) * 128;

  __shared__ __align__(16) unsigned short Asm[128][72];
  __shared__ __align__(16) unsigned short Bsm[128][72];

  const int tid = threadIdx.x;
  const int wid = tid >> 6, l = tid & 63;
  const int lg = l >> 4, li = l & 15;
  const int wm = (wid >> 1) * 64, wn = (wid & 1) * 64;
  const int srow = tid >> 1, shalf = (tid & 1) * 32;

  f32x4 acc[4][4];
  #pragma unroll
  for (int i = 0; i < 4; ++i)
    #pragma unroll
    for (int j = 0; j < 4; ++j) acc[i][j] = (f32x4){0.f, 0.f, 0.f, 0.f};

  for (int kt = 0; kt < E_; kt += 64) {
    const short* ga = hsb + (size_t)(m0 + srow) * E_ + kt + shalf;
    const short* gb = Wsel + (size_t)(nb + srow) * E_ + kt + shalf;
    f16x8 a0 = *(const f16x8*)(ga);      f16x8 a1 = *(const f16x8*)(ga + 8);
    f16x8 a2 = *(const f16x8*)(ga + 16); f16x8 a3 = *(const f16x8*)(ga + 24);
    f16x8 b0 = *(const f16x8*)(gb);      f16x8 b1 = *(const f16x8*)(gb + 8);
    f16x8 b2 = *(const f16x8*)(gb + 16); f16x8 b3 = *(const f16x8*)(gb + 24);
    __syncthreads();
    *(f16x8*)&Asm[srow][shalf + 0]  = a0; *(f16x8*)&Asm[srow][shalf + 8]  = a1;
    *(f16x8*)&Asm[srow][shalf + 16] = a2; *(f16x8*)&Asm[srow][shalf + 24] = a3;
    *(f16x8*)&Bsm[srow][shalf + 0]  = b0; *(f16x8*)&Bsm[srow][shalf + 8]  = b1;
    *(f16x8*)&Bsm[srow][shalf + 16] = b2; *(f16x8*)&Bsm[srow][shalf + 24] = b3;
    __syncthreads();
    #pragma unroll
    for (int kb = 0; kb < 2; ++kb) {
      f16x8 af[4], bfv[4];
      #pragma unroll
      for (int i = 0; i < 4; ++i)
        af[i] = *(const f16x8*)&Asm[wm + i * 16 + li][kb * 32 + lg * 8];
      #pragma unroll
      for (int j = 0; j < 4; ++j)
        bfv[j] = *(const f16x8*)&Bsm[wn + j * 16 + li][kb * 32 + lg * 8];
      #pragma unroll
      for (int i = 0; i < 4; ++i)
        #pragma unroll
        for (int j = 0; j < 4; ++j)
          acc[i][j] = __builtin_amdgcn_mfma_f32_16x16x32_f16(af[i], bfv[j], acc[i][j], 0, 0, 0);
    }
  }

  #pragma unroll
  for (int j = 0; j < 4; ++j) {
    const int n = nb + wn + j * 16 + li;
    const float bv = bsel[n];
    #pragma unroll
    for (int i = 0; i < 4; ++i) {
      #pragma unroll
      for (int r = 0; r < 4; ++r) {
        const int m = m0 + wm + i * 16 + lg * 4 + r;
        Csel[(size_t)m * E_ + n] = f2h(acc[i][j][r] + bv);
      }
    }
  }
}

// ----------------- K2a: z sums via causal 128x128 GEMM tiles ---------------
__global__ __launch_bounds__(256) void zpart_kernel(
    const short* __restrict__ Qh, const short* __restrict__ Kh,
    const int* __restrict__ clen, float* __restrict__ zs)
{
  const int bh = blockIdx.y;
  const int b = bh >> 4, h = bh & 15;
  int ti, si;
  tri_decode(blockIdx.x, ti, si);
  const int t0 = ti * 128, s0 = si * 128;
  const int tid = threadIdx.x;
  const int w = tid >> 6, l = tid & 63, lg = l >> 4, li = l & 15;
  const int wm = (w >> 1) * 64, wn = (w & 1) * 64;

  __shared__ __align__(16) unsigned short Qs[128][72];
  __shared__ __align__(16) unsigned short Ks[128][72];
  __shared__ int len_s[128];

  {
    const int row = tid >> 1, half = (tid & 1) * 32;
    const short* gq = Qh + (size_t)(b * T_ + t0 + row) * E_ + h * DH_ + half;
    const short* gk = Kh + (size_t)(b * T_ + s0 + row) * E_ + h * DH_ + half;
    *(f16x8*)&Qs[row][half + 0]  = *(const f16x8*)(gq + 0);
    *(f16x8*)&Qs[row][half + 8]  = *(const f16x8*)(gq + 8);
    *(f16x8*)&Qs[row][half + 16] = *(const f16x8*)(gq + 16);
    *(f16x8*)&Qs[row][half + 24] = *(const f16x8*)(gq + 24);
    *(f16x8*)&Ks[row][half + 0]  = *(const f16x8*)(gk + 0);
    *(f16x8*)&Ks[row][half + 8]  = *(const f16x8*)(gk + 8);
    *(f16x8*)&Ks[row][half + 16] = *(const f16x8*)(gk + 16);
    *(f16x8*)&Ks[row][half + 24] = *(const f16x8*)(gk + 24);
  }
  if (tid < 128) {
    int L = clen[t0 + tid];
    len_s[tid] = L < 0 ? 0 : (L > T_ ? T_ : L);
  }
  __syncthreads();

  f32x4 acc[4][4];
  #pragma unroll
  for (int i = 0; i < 4; ++i)
    #pragma unroll
    for (int j = 0; j < 4; ++j) acc[i][j] = (f32x4){0.f, 0.f, 0.f, 0.f};

  #pragma unroll
  for (int kb = 0; kb < 2; ++kb) {
    f16x8 af[4], bfv[4];
    #pragma unroll
    for (int i = 0; i < 4; ++i)
      af[i] = *(const f16x8*)&Qs[wm + i * 16 + li][kb * 32 + lg * 8];
    #pragma unroll
    for (int j = 0; j < 4; ++j)
      bfv[j] = *(const f16x8*)&Ks[wn + j * 16 + li][kb * 32 + lg * 8];
    #pragma unroll
    for (int i = 0; i < 4; ++i)
      #pragma unroll
      for (int j = 0; j < 4; ++j)
        acc[i][j] = __builtin_amdgcn_mfma_f32_16x16x32_f16(af[i], bfv[j], acc[i][j], 0, 0, 0);
  }

  float zp[4][4];
  #pragma unroll
  for (int i = 0; i < 4; ++i)
    #pragma unroll
    for (int r = 0; r < 4; ++r) zp[i][r] = 0.f;

  #pragma unroll
  for (int i = 0; i < 4; ++i) {
    int lenr[4];
    #pragma unroll
    for (int r = 0; r < 4; ++r) lenr[r] = len_s[wm + i * 16 + lg * 4 + r];
    #pragma unroll
    for (int j = 0; j < 4; ++j) {
      const int scol = s0 + wn + j * 16 + li;
      #pragma unroll
      for (int r = 0; r < 4; ++r)
        if (scol < lenr[r]) zp[i][r] += __expf(acc[i][j][r] * SCALE_);
    }
  }

  #pragma unroll
  for (int i = 0; i < 4; ++i)
    #pragma unroll
    for (int r = 0; r < 4; ++r) {
      float v = zp[i][r];
      v += __shfl_xor(v, 1); v += __shfl_xor(v, 2);
      v += __shfl_xor(v, 4); v += __shfl_xor(v, 8);
      if (li == 0 && v > 0.f)
        atomicAdd(&zs[(size_t)bh * T_ + t0 + wm + i * 16 + lg * 4 + r], v);
    }
}

// ---------- K2b: causal 64x64 tiles, head-PAIR loop, EL + L ----------------
__global__ __launch_bounds__(256) void elgen_kernel(
    const short* __restrict__ Qh, const short* __restrict__ Kh,
    const float* __restrict__ zs, const float* __restrict__ gum,
    const int* __restrict__ clen,
    short* __restrict__ EL, float* __restrict__ Lws)
{
  const int b = blockIdx.y;
  int ti, si;
  tri_decode(blockIdx.x, ti, si);
  const int t0 = ti * 64, s0 = si * 64;
  const int tid = threadIdx.x;
  const int w = tid >> 6, l = tid & 63, lg = l >> 4, li = l & 15;
  const int wr = (w >> 1) * 32, wc = (w & 1) * 32;

  __shared__ __align__(16) unsigned short Qs[64][136];   // head pair: 128 k-dims
  __shared__ __align__(16) unsigned short Ks[64][136];
  __shared__ float rz_s[16][64];
  __shared__ int len_s[64];

  if (tid < 64) {
    int L = clen[t0 + tid];
    len_s[tid] = L < 0 ? 0 : (L > T_ ? T_ : L);
  }
  #pragma unroll
  for (int q = 0; q < 4; ++q) {
    const int e = tid * 4 + q;                    // 0..1023 = h*64 + tl
    const float zv = zs[(size_t)(b * NH_ + (e >> 6)) * T_ + t0 + (e & 63)];
    rz_s[e >> 6][e & 63] = (zv > 0.f) ? 1.f / zv : 0.f;
  }

  f32x4 aw[2][2];
  #pragma unroll
  for (int i = 0; i < 2; ++i)
    #pragma unroll
    for (int j = 0; j < 2; ++j) aw[i][j] = (f32x4){0.f, 0.f, 0.f, 0.f};

  const int srow = tid >> 2, sch = (tid & 3) * 32;

  for (int p = 0; p < 8; ++p) {                   // head pair (2p, 2p+1)
    __syncthreads();
    const short* gq = Qh + (size_t)(b * T_ + t0 + srow) * E_ + p * 128 + sch;
    const short* gk = Kh + (size_t)(b * T_ + s0 + srow) * E_ + p * 128 + sch;
    *(f16x8*)&Qs[srow][sch + 0]  = *(const f16x8*)(gq);
    *(f16x8*)&Qs[srow][sch + 8]  = *(const f16x8*)(gq + 8);
    *(f16x8*)&Qs[srow][sch + 16] = *(const f16x8*)(gq + 16);
    *(f16x8*)&Qs[srow][sch + 24] = *(const f16x8*)(gq + 24);
    *(f16x8*)&Ks[srow][sch + 0]  = *(const f16x8*)(gk);
    *(f16x8*)&Ks[srow][sch + 8]  = *(const f16x8*)(gk + 8);
    *(f16x8*)&Ks[srow][sch + 16] = *(const f16x8*)(gk + 16);
    *(f16x8*)&Ks[srow][sch + 24] = *(const f16x8*)(gk + 24);
    __syncthreads();

    f32x4 sc[2][2][2];                            // [head][i][j]
    #pragma unroll
    for (int h2 = 0; h2 < 2; ++h2)
      #pragma unroll
      for (int i = 0; i < 2; ++i)
        #pragma unroll
        for (int j = 0; j < 2; ++j) sc[h2][i][j] = (f32x4){0.f, 0.f, 0.f, 0.f};

    #pragma unroll
    for (int h2 = 0; h2 < 2; ++h2) {
      #pragma unroll
      for (int kb = 0; kb < 2; ++kb) {
        const int kc = h2 * 64 + kb * 32 + lg * 8;
        f16x8 af[2], bfv[2];
        af[0] = *(const f16x8*)&Qs[wr + li][kc];
        af[1] = *(const f16x8*)&Qs[wr + 16 + li][kc];
        bfv[0] = *(const f16x8*)&Ks[wc + li][kc];
        bfv[1] = *(const f16x8*)&Ks[wc + 16 + li][kc];
        #pragma unroll
        for (int i = 0; i < 2; ++i)
          #pragma unroll
          for (int j = 0; j < 2; ++j)
            sc[h2][i][j] = __builtin_amdgcn_mfma_f32_16x16x32_f16(af[i], bfv[j], sc[h2][i][j], 0, 0, 0);
      }
    }
    #pragma unroll
    for (int i = 0; i < 2; ++i) {
      float rz0[4], rz1[4];
      #pragma unroll
      for (int r = 0; r < 4; ++r) {
        rz0[r] = rz_s[2 * p][wr + i * 16 + lg * 4 + r];
        rz1[r] = rz_s[2 * p + 1][wr + i * 16 + lg * 4 + r];
      }
      #pragma unroll
      for (int j = 0; j < 2; ++j)
        #pragma unroll
        for (int r = 0; r < 4; ++r)
          aw[i][j][r] += __expf(sc[0][i][j][r] * SCALE_) * rz0[r] +
                         __expf(sc[1][i][j][r] * SCALE_) * rz1[r];
    }
  }

  // epilogue: gumbel -> EL fp16 store + L row partials
  #pragma unroll
  for (int i = 0; i < 2; ++i) {
    float lrow[4] = {0.f, 0.f, 0.f, 0.f};
    #pragma unroll
    for (int r = 0; r < 4; ++r) {
      const int tl = wr + i * 16 + lg * 4 + r;
      const int lenr = len_s[tl];
      const size_t grow = (size_t)(b * T_ + t0 + tl) * T_;
      #pragma unroll
      for (int j = 0; j < 2; ++j) {
        const int scol = s0 + wc + j * 16 + li;
        float e = 0.f;
        if (scol < lenr) {
          const float u = gum[grow + scol];
          const float g = -__logf(-__logf(u));
          e = expf((aw[i][j][r] * (1.f / NH_) + g) * 0.5f);   // /TAU, TAU=2
        }
        EL[grow + scol] = f2h(e);
        lrow[r] += e;
      }
    }
    #pragma unroll
    for (int r = 0; r < 4; ++r) {
      float v = lrow[r];
      v += __shfl_xor(v, 1); v += __shfl_xor(v, 2);
      v += __shfl_xor(v, 4); v += __shfl_xor(v, 8);
      if (li == 0 && v > 0.f)
        atomicAdd(&Lws[(size_t)(b * T_) + t0 + wr + i * 16 + lg * 4 + r], v);
    }
  }
}

// ----------------------- K3: output MFMA + normalize -----------------------
// Single-pass fp16: 64x64 tile, BK=64, grid (E/64, M/64)=1024 -> 4 blocks/CU.
__global__ __launch_bounds__(256) void out_mfma(
    const short* __restrict__ EL, const short* __restrict__ HT,
    const float* __restrict__ Lws, const int* __restrict__ clen,
    float* __restrict__ outp)
{
  const int e0 = blockIdx.x * 64;
  const int m0 = ((int)gridDim.y - 1 - (int)blockIdx.y) * 64;   // long tiles first
  const int b = m0 >> 11;
  const int tl0 = m0 & (T_ - 1);
  const int tid = threadIdx.x;
  const int w = tid >> 6, l = tid & 63, lg = l >> 4, li = l & 15;

  __shared__ __align__(16) unsigned short As[64][72];
  __shared__ __align__(16) unsigned short Bs[64][72];
  __shared__ int smax_sh;

  if (tid == 0) smax_sh = 0;
  __syncthreads();
  if (tid < 64) {
    int L = clen[tl0 + tid];
    L = L < 0 ? 0 : (L > T_ ? T_ : L);
    atomicMax(&smax_sh, L);
  }
  __syncthreads();
  const int kend = (smax_sh + 63) & ~63;   // <= tl0+64: stays in causal EL tiles

  const int srow = tid >> 2, sc16 = (tid & 3) * 16;

  f32x4 acc[4];
  #pragma unroll
  for (int j = 0; j < 4; ++j) acc[j] = (f32x4){0.f, 0.f, 0.f, 0.f};

  for (int s0 = 0; s0 < kend; s0 += 64) {
    const size_t asrc = (size_t)(m0 + srow) * T_ + s0 + sc16;
    const size_t bsrc = (size_t)(b * E_ + e0 + srow) * T_ + s0 + sc16;
    const f16x8 va0 = *(const f16x8*)(EL + asrc);
    const f16x8 va1 = *(const f16x8*)(EL + asrc + 8);
    const f16x8 vb0 = *(const f16x8*)(HT + bsrc);
    const f16x8 vb1 = *(const f16x8*)(HT + bsrc + 8);
    __syncthreads();
    *(f16x8*)&As[srow][sc16] = va0; *(f16x8*)&As[srow][sc16 + 8] = va1;
    *(f16x8*)&Bs[srow][sc16] = vb0; *(f16x8*)&Bs[srow][sc16 + 8] = vb1;
    __syncthreads();
    #pragma unroll
    for (int kb = 0; kb < 2; ++kb) {
      const f16x8 af = *(const f16x8*)&As[w * 16 + li][kb * 32 + lg * 8];
      f16x8 bfv[4];
      #pragma unroll
      for (int j = 0; j < 4; ++j)
        bfv[j] = *(const f16x8*)&Bs[j * 16 + li][kb * 32 + lg * 8];
      #pragma unroll
      for (int j = 0; j < 4; ++j)
        acc[j] = __builtin_amdgcn_mfma_f32_16x16x32_f16(af, bfv[j], acc[j], 0, 0, 0);
    }
  }

  #pragma unroll
  for (int r = 0; r < 4; ++r) {
    const int m = m0 + w * 16 + lg * 4 + r;
    const float Lv = Lws[m];
    const float inv = (Lv > 0.f) ? 1.f / Lv : 0.f;
    #pragma unroll
    for (int j = 0; j < 4; ++j)
      outp[(size_t)m * E_ + e0 + j * 16 + li] = acc[j][r] * inv;
  }
}

// ------------------------------- launcher ----------------------------------
extern "C" void kernel_launch(void* const* d_in, const int* in_sizes, int n_in,
                              void* d_out, int out_size, void* d_ws, size_t ws_size,
                              hipStream_t stream) {
  const float* hs  = (const float*)d_in[0];
  const float* Wq  = (const float*)d_in[1];
  const float* bq  = (const float*)d_in[2];
  const float* Wk  = (const float*)d_in[3];
  const float* bk  = (const float*)d_in[4];
  const float* gum = (const float*)d_in[5];
  const int*   cl  = (const int*)d_in[6];
  float* out = (float*)d_out;

  short* hs16  = (short*)d_ws;
  short* hsT16 = hs16  + (size_t)M_ * E_;
  short* Wq16  = hsT16 + (size_t)B_ * E_ * T_;
  short* Wk16  = Wq16 + (size_t)E_ * E_;
  short* Qh    = Wk16 + (size_t)E_ * E_;
  short* Kh    = Qh + (size_t)M_ * E_;
  short* ELws  = Kh + (size_t)M_ * E_;
  float* zsws  = (float*)(ELws + (size_t)M_ * T_);
  float* Lw    = zsws + (size_t)B_ * NH_ * T_;
  (void)ws_size; (void)in_sizes; (void)n_in; (void)out_size;

  hipMemsetAsync(zsws, 0, (size_t)B_ * NH_ * T_ * sizeof(float), stream);
  hipMemsetAsync(Lw, 0, (size_t)M_ * sizeof(float), stream);
  prep_hs<<<dim3(T_ / 64, E_ / 64, B_), 256, 0, stream>>>(hs, hs16, hsT16);
  cast_w<<<dim3((E_ * E_) / (256 * 4)), 256, 0, stream>>>(Wq, Wk, Wq16, Wk16);
  proj_mfma<<<dim3(16, M_ / 128), 256, 0, stream>>>(hs16, Wq16, Wk16, bq, bk, Qh, Kh);
  zpart_kernel<<<dim3(136, B_ * NH_), 256, 0, stream>>>(Qh, Kh, cl, zsws);
  elgen_kernel<<<dim3(528, B_), 256, 0, stream>>>(Qh, Kh, zsws, gum, cl, ELws, Lw);
  out_mfma<<<dim3(E_ / 64, M_ / 64), 256, 0, stream>>>(ELws, hsT16, Lw, cl, out);
}